// Round 4
// baseline (326.872 us; speedup 1.0000x reference)
//
#include <hip/hip_runtime.h>

// AttentionGate: out[b,cf,v] = x[b,cf,v] * sigmoid(Wpsi · relu(Wg·g[b,:,v] + Wx·x[b,:,v]))
// B=2, CF=CG=64, CI=32, SPAT=64^3. fp32.
//
// R6: kill the epilogue x re-read. R2/R3/R5 proved: occupancy (20-70%), load
// width (4/8/16B), manual pipelining — all land 108-115 µs @ ~3 TB/s HBM. But
// total through-cache traffic is 536 MB (x+g read, x RE-read, out write) in
// 110 µs = 4.9 TB/s at the L2/L3 level — near the real mixed-stream ceiling.
// Minimum traffic is 403 MB: the removable third is the x re-read. Fix: park
// x in LDS during the main loop, read it back from LDS in the epilogue.
// xs[64][256] = 64 KB/block (2 blocks/CU), each thread touches only its own
// column -> conflict-free (lane-consecutive, free 2-way) and NO barrier needed.
// Registers stay ~64 VGPR (R4 showed register-hoarding spills; full unroll
// with xr[64] would blow the 32 KB I$). g stays nontemporal (read-once),
// out stays nontemporal (write-once), x normal (inter-dispatch L3 retention).

#define SPAT 262144        // 64*64*64 voxels per (b,c) plane, 2^18
#define NVOX 524288        // B * SPAT
#define CIN  64
#define COUT 32

__global__ __launch_bounds__(256) void transpose_w(const float* __restrict__ Wg,
                                                   const float* __restrict__ Wx,
                                                   float* __restrict__ Wcat) {
    int idx = blockIdx.x * 256 + threadIdx.x;   // 0..4095
    int c = idx >> 6;
    int o = idx & 63;
    float v = (o < 32) ? Wg[o * CIN + c] : Wx[(o - 32) * CIN + c];
    Wcat[c * 64 + o] = v;
}

__global__ __launch_bounds__(256) void gate_main(const float* __restrict__ x,
                                                 const float* __restrict__ g,
                                                 const float* __restrict__ Wcat,
                                                 const float* __restrict__ Wpsi,
                                                 float* __restrict__ out) {
    __shared__ float xs[CIN][256];              // 64 KB: x parked for the epilogue

    int tid = threadIdx.x;
    int p = blockIdx.x * 256 + tid;             // voxel index 0..524287
    int b = p >> 18;                            // SPAT = 2^18
    int s = p & (SPAT - 1);

    const float* __restrict__ xp = x + (size_t)b * CIN * SPAT + s;
    const float* __restrict__ gp = g + (size_t)b * CIN * SPAT + s;

    float acc[COUT];
#pragma unroll
    for (int o = 0; o < COUT; ++o) acc[o] = 0.0f;

#pragma unroll 4
    for (int c = 0; c < CIN; ++c) {
        float gc = __builtin_nontemporal_load(gp + (size_t)c * SPAT);  // g read once
        float xc = xp[(size_t)c * SPAT];                               // x read ONCE
        xs[c][tid] = xc;                        // park for epilogue (own column, no conflict)
        const float* w = Wcat + c * 64;         // wave-uniform -> scalar loads
#pragma unroll
        for (int o = 0; o < COUT; ++o) {
            acc[o] = fmaf(w[o], gc, fmaf(w[32 + o], xc, acc[o]));
        }
    }

    float ps = 0.0f;
#pragma unroll
    for (int o = 0; o < COUT; ++o) {
        ps = fmaf(Wpsi[o], fmaxf(acc[o], 0.0f), ps);
    }
    float psi = 1.0f / (1.0f + __expf(-ps));

    // epilogue: x comes from LDS (own column), only stores touch global
    float* __restrict__ op = out + (size_t)b * CIN * SPAT + s;
#pragma unroll 8
    for (int c = 0; c < CIN; ++c) {
        __builtin_nontemporal_store(xs[c][tid] * psi, op + (size_t)c * SPAT);
    }
}

extern "C" void kernel_launch(void* const* d_in, const int* in_sizes, int n_in,
                              void* d_out, int out_size, void* d_ws, size_t ws_size,
                              hipStream_t stream) {
    const float* x    = (const float*)d_in[0];
    const float* g    = (const float*)d_in[1];
    const float* Wg   = (const float*)d_in[2];
    const float* Wx   = (const float*)d_in[3];
    const float* Wpsi = (const float*)d_in[4];
    float* out  = (float*)d_out;
    float* Wcat = (float*)d_ws;                 // 64*64 floats = 16 KB scratch

    transpose_w<<<16, 256, 0, stream>>>(Wg, Wx, Wcat);
    gate_main<<<NVOX / 256, 256, 0, stream>>>(x, g, Wcat, Wpsi, out);
}